// Round 1
// baseline (229.478 us; speedup 1.0000x reference)
//
#include <hip/hip_runtime.h>
#include <hip/hip_bf16.h>

#define BB 2
#define SS 2048
#define DD 1024
#define HH 16
#define DHH 64

typedef __attribute__((ext_vector_type(8))) __bf16 bf16x8;
typedef __attribute__((ext_vector_type(4))) float f32x4;
typedef __attribute__((ext_vector_type(4))) int i32x4;

#define MFMA __builtin_amdgcn_mfma_f32_16x16x32_bf16

__device__ __forceinline__ unsigned short f2b(float f) {
  __hip_bfloat16 h = __float2bfloat16(f);
  unsigned short u;
  __builtin_memcpy(&u, &h, 2);
  return u;
}

// ---------------- cast fp32 -> bf16 (x4 vectorized) ----------------
__global__ __launch_bounds__(256) void k_cast(const float* __restrict__ in,
                                              unsigned short* __restrict__ out, int n4) {
  int i = blockIdx.x * blockDim.x + threadIdx.x;
  if (i >= n4) return;
  float4 v = ((const float4*)in)[i];
  ushort4 o;
  o.x = f2b(v.x); o.y = f2b(v.y); o.z = f2b(v.z); o.w = f2b(v.w);
  ((ushort4*)out)[i] = o;
}

// ------- transpose+cast: per-matrix fp32 [R][C] -> bf16 [C][R] -------
__global__ __launch_bounds__(256) void k_tcast(const float* __restrict__ in,
                                               unsigned short* __restrict__ out, int R, int C) {
  __shared__ float t[32][33];
  size_t mb = (size_t)blockIdx.z * R * C;
  const float* im = in + mb;
  unsigned short* om = out + mb;
  int c0 = blockIdx.x * 32, r0 = blockIdx.y * 32;
  int tx = threadIdx.x & 31, ty = threadIdx.x >> 5;
#pragma unroll
  for (int rr = ty; rr < 32; rr += 8)
    t[rr][tx] = im[(size_t)(r0 + rr) * C + c0 + tx];
  __syncthreads();
#pragma unroll
  for (int rr = ty; rr < 32; rr += 8)
    om[(size_t)(c0 + rr) * R + r0 + tx] = f2b(t[tx][rr]);
}

// ------- transpose bf16: per-matrix [R][C] -> [C][R] -------
__global__ __launch_bounds__(256) void k_tbf16(const unsigned short* __restrict__ in,
                                               unsigned short* __restrict__ out, int R, int C) {
  __shared__ unsigned short t[32][34];
  size_t mb = (size_t)blockIdx.z * R * C;
  const unsigned short* im = in + mb;
  unsigned short* om = out + mb;
  int c0 = blockIdx.x * 32, r0 = blockIdx.y * 32;
  int tx = threadIdx.x & 31, ty = threadIdx.x >> 5;
#pragma unroll
  for (int rr = ty; rr < 32; rr += 8)
    t[rr][tx] = im[(size_t)(r0 + rr) * C + c0 + tx];
  __syncthreads();
#pragma unroll
  for (int rr = ty; rr < 32; rr += 8)
    om[(size_t)(c0 + rr) * R + r0 + tx] = t[tx][rr];
}

// ---------------- QKV GEMM: [4096,1024] x [48 mats of 64x1024^T] ----------------
// A: xb bf16 [B*S][D].  Wt: [3*H][DH][D] (N-major, K contiguous).
__global__ __launch_bounds__(256) void k_qkv(const unsigned short* __restrict__ A,
                                             const unsigned short* __restrict__ Wt,
                                             const float* __restrict__ bq,
                                             const float* __restrict__ bk,
                                             const float* __restrict__ bv,
                                             unsigned short* __restrict__ Qb,
                                             unsigned short* __restrict__ Kb,
                                             unsigned short* __restrict__ Vb) {
  __shared__ __align__(16) unsigned short As[64][72];
  __shared__ __align__(16) unsigned short Bs[64][72];
  int tid = threadIdx.x;
  int w = tid >> 6, lane = tid & 63, lr = lane & 15, lg = lane >> 4;
  int c0 = blockIdx.x * 64;   // 0..3071
  int row0 = blockIdx.y * 64; // 0..4095
  int sel = c0 >> 10;
  int h = (c0 & 1023) >> 6;
  const unsigned short* Bm = Wt + (size_t)(sel * HH + h) * DHH * DD;
  const float* biasp = sel == 0 ? bq : (sel == 1 ? bk : bv);
  unsigned short* outp = sel == 0 ? Qb : (sel == 1 ? Kb : Vb);

  int sr = tid >> 2, se = (tid & 3) * 8;
  const unsigned short* a_src = A + (size_t)(row0 + sr) * DD + se;
  const unsigned short* b_src = Bm + (size_t)sr * DD + se;
  unsigned short* a_dst = &As[sr][se];
  unsigned short* b_dst = &Bs[sr][se];

  f32x4 zero = {0.f, 0.f, 0.f, 0.f};
  f32x4 acc[4];
#pragma unroll
  for (int i = 0; i < 4; i++) acc[i] = zero;

  for (int k0 = 0; k0 < DD; k0 += 64) {
    __syncthreads();
    *(i32x4*)a_dst        = *(const i32x4*)(a_src + k0);
    *(i32x4*)(a_dst + 32) = *(const i32x4*)(a_src + k0 + 32);
    *(i32x4*)b_dst        = *(const i32x4*)(b_src + k0);
    *(i32x4*)(b_dst + 32) = *(const i32x4*)(b_src + k0 + 32);
    __syncthreads();
#pragma unroll
    for (int kk = 0; kk < 2; kk++) {
      bf16x8 af = *(const bf16x8*)&As[16 * w + lr][32 * kk + lg * 8];
#pragma unroll
      for (int cb = 0; cb < 4; cb++) {
        bf16x8 bfr = *(const bf16x8*)&Bs[16 * cb + lr][32 * kk + lg * 8];
        acc[cb] = MFMA(af, bfr, acc[cb], 0, 0, 0);
      }
    }
  }
#pragma unroll
  for (int cb = 0; cb < 4; cb++) {
    int d = 16 * cb + lr;
    float bias = biasp[h * DHH + d];
#pragma unroll
    for (int r = 0; r < 4; r++) {
      int grow = row0 + 16 * w + lg * 4 + r;
      int b = grow >> 11, s = grow & 2047;
      outp[((size_t)(b * HH + h) * SS + s) * DHH + d] = f2b(acc[cb][r] + bias);
    }
  }
}

// ---------------- output projection GEMM ----------------
// A: Ocat bf16 [4096][1024]. Wt: Wo^T bf16 [1024][1024] (o-major). out fp32 + bias.
__global__ __launch_bounds__(256) void k_proj(const unsigned short* __restrict__ A,
                                              const unsigned short* __restrict__ Wt,
                                              const float* __restrict__ bo,
                                              float* __restrict__ out) {
  __shared__ __align__(16) unsigned short As[64][72];
  __shared__ __align__(16) unsigned short Bs[64][72];
  int tid = threadIdx.x;
  int w = tid >> 6, lane = tid & 63, lr = lane & 15, lg = lane >> 4;
  int c0 = blockIdx.x * 64;
  int row0 = blockIdx.y * 64;

  int sr = tid >> 2, se = (tid & 3) * 8;
  const unsigned short* a_src = A + (size_t)(row0 + sr) * DD + se;
  const unsigned short* b_src = Wt + (size_t)(c0 + sr) * DD + se;
  unsigned short* a_dst = &As[sr][se];
  unsigned short* b_dst = &Bs[sr][se];

  f32x4 zero = {0.f, 0.f, 0.f, 0.f};
  f32x4 acc[4];
#pragma unroll
  for (int i = 0; i < 4; i++) acc[i] = zero;

  for (int k0 = 0; k0 < DD; k0 += 64) {
    __syncthreads();
    *(i32x4*)a_dst        = *(const i32x4*)(a_src + k0);
    *(i32x4*)(a_dst + 32) = *(const i32x4*)(a_src + k0 + 32);
    *(i32x4*)b_dst        = *(const i32x4*)(b_src + k0);
    *(i32x4*)(b_dst + 32) = *(const i32x4*)(b_src + k0 + 32);
    __syncthreads();
#pragma unroll
    for (int kk = 0; kk < 2; kk++) {
      bf16x8 af = *(const bf16x8*)&As[16 * w + lr][32 * kk + lg * 8];
#pragma unroll
      for (int cb = 0; cb < 4; cb++) {
        bf16x8 bfr = *(const bf16x8*)&Bs[16 * cb + lr][32 * kk + lg * 8];
        acc[cb] = MFMA(af, bfr, acc[cb], 0, 0, 0);
      }
    }
  }
#pragma unroll
  for (int cb = 0; cb < 4; cb++) {
    int c = c0 + 16 * cb + lr;
    float bias = bo[c];
#pragma unroll
    for (int r = 0; r < 4; r++) {
      int grow = row0 + 16 * w + lg * 4 + r;
      out[(size_t)grow * DD + c] = acc[cb][r] + bias;
    }
  }
}

// ---------------- flash attention ----------------
// Q,K: [B*H][S][DH] bf16. Vt: [B*H][DH][S] bf16. Ocat: [B][S][H*DH] bf16.
__global__ __launch_bounds__(256) void k_attn(const unsigned short* __restrict__ Q,
                                              const unsigned short* __restrict__ K,
                                              const unsigned short* __restrict__ Vt,
                                              unsigned short* __restrict__ Ocat) {
  __shared__ __align__(16) unsigned short Qs[64][72];
  __shared__ __align__(16) unsigned short Ks[64][72];
  __shared__ __align__(16) unsigned short Vs[64][72];
  __shared__ __align__(16) unsigned short Ps[4][16][72];

  int tid = threadIdx.x;
  int w = tid >> 6, lane = tid & 63, lr = lane & 15, lg = lane >> 4;
  int bh = blockIdx.y;
  int b = bh >> 4, h = bh & 15;
  int q0 = blockIdx.x * 64;
  const unsigned short* Qm = Q + (size_t)bh * SS * DHH;
  const unsigned short* Km = K + (size_t)bh * SS * DHH;
  const unsigned short* Vm = Vt + (size_t)bh * DHH * SS;

  int sr = tid >> 2, se = (tid & 3) * 8;

  {
    const unsigned short* src = Qm + (size_t)(q0 + sr) * DHH;
    *(i32x4*)&Qs[sr][se]      = *(const i32x4*)(src + se);
    *(i32x4*)&Qs[sr][se + 32] = *(const i32x4*)(src + se + 32);
  }
  __syncthreads();
  bf16x8 qf[2];
  qf[0] = *(const bf16x8*)&Qs[16 * w + lr][lg * 8];
  qf[1] = *(const bf16x8*)&Qs[16 * w + lr][32 + lg * 8];

  f32x4 zero = {0.f, 0.f, 0.f, 0.f};
  f32x4 oacc[4];
#pragma unroll
  for (int i = 0; i < 4; i++) oacc[i] = zero;
  float m[4], l[4];
#pragma unroll
  for (int r = 0; r < 4; r++) { m[r] = -INFINITY; l[r] = 0.f; }
  const float scale = 0.125f;

  for (int kv0 = 0; kv0 < SS; kv0 += 64) {
    __syncthreads();
    {
      const unsigned short* ksrc = Km + (size_t)(kv0 + sr) * DHH;
      *(i32x4*)&Ks[sr][se]      = *(const i32x4*)(ksrc + se);
      *(i32x4*)&Ks[sr][se + 32] = *(const i32x4*)(ksrc + se + 32);
      const unsigned short* vsrc = Vm + (size_t)sr * SS + kv0;
      *(i32x4*)&Vs[sr][se]      = *(const i32x4*)(vsrc + se);
      *(i32x4*)&Vs[sr][se + 32] = *(const i32x4*)(vsrc + se + 32);
    }
    __syncthreads();

    f32x4 sacc[4];
#pragma unroll
    for (int i = 0; i < 4; i++) sacc[i] = zero;
#pragma unroll
    for (int kk = 0; kk < 2; kk++) {
#pragma unroll
      for (int cb = 0; cb < 4; cb++) {
        bf16x8 kfr = *(const bf16x8*)&Ks[16 * cb + lr][32 * kk + lg * 8];
        sacc[cb] = MFMA(qf[kk], kfr, sacc[cb], 0, 0, 0);
      }
    }
#pragma unroll
    for (int i = 0; i < 4; i++) sacc[i] *= scale;

    float rmax[4];
#pragma unroll
    for (int r = 0; r < 4; r++)
      rmax[r] = fmaxf(fmaxf(sacc[0][r], sacc[1][r]), fmaxf(sacc[2][r], sacc[3][r]));
#pragma unroll
    for (int off = 1; off < 16; off <<= 1) {
#pragma unroll
      for (int r = 0; r < 4; r++)
        rmax[r] = fmaxf(rmax[r], __shfl_xor(rmax[r], off));
    }

    float al[4];
#pragma unroll
    for (int r = 0; r < 4; r++) {
      float mn = fmaxf(m[r], rmax[r]);
      al[r] = __expf(m[r] - mn);
      m[r] = mn;
      l[r] *= al[r];
    }
#pragma unroll
    for (int cb = 0; cb < 4; cb++)
#pragma unroll
      for (int r = 0; r < 4; r++)
        oacc[cb][r] *= al[r];

    float psum[4] = {0.f, 0.f, 0.f, 0.f};
#pragma unroll
    for (int cb = 0; cb < 4; cb++) {
#pragma unroll
      for (int r = 0; r < 4; r++) {
        float p = __expf(sacc[cb][r] - m[r]);
        sacc[cb][r] = p;
        psum[r] += p;
      }
    }
#pragma unroll
    for (int off = 1; off < 16; off <<= 1) {
#pragma unroll
      for (int r = 0; r < 4; r++)
        psum[r] += __shfl_xor(psum[r], off);
    }
#pragma unroll
    for (int r = 0; r < 4; r++) l[r] += psum[r];

#pragma unroll
    for (int cb = 0; cb < 4; cb++)
#pragma unroll
      for (int r = 0; r < 4; r++)
        Ps[w][lg * 4 + r][16 * cb + lr] = f2b(sacc[cb][r]);
    __syncthreads();

#pragma unroll
    for (int kk = 0; kk < 2; kk++) {
      bf16x8 pa = *(const bf16x8*)&Ps[w][lr][32 * kk + lg * 8];
#pragma unroll
      for (int cb = 0; cb < 4; cb++) {
        bf16x8 vf = *(const bf16x8*)&Vs[16 * cb + lr][32 * kk + lg * 8];
        oacc[cb] = MFMA(pa, vf, oacc[cb], 0, 0, 0);
      }
    }
  }

#pragma unroll
  for (int cb = 0; cb < 4; cb++) {
#pragma unroll
    for (int r = 0; r < 4; r++) {
      int s = q0 + 16 * w + lg * 4 + r;
      float o = oacc[cb][r] / l[r];
      Ocat[((size_t)(b * SS + s)) * DD + h * DHH + 16 * cb + lr] = f2b(o);
    }
  }
}

extern "C" void kernel_launch(void* const* d_in, const int* in_sizes, int n_in,
                              void* d_out, int out_size, void* d_ws, size_t ws_size,
                              hipStream_t stream) {
  const float* x  = (const float*)d_in[0];
  const float* Wq = (const float*)d_in[1];
  const float* bq = (const float*)d_in[2];
  const float* Wk = (const float*)d_in[3];
  const float* bk = (const float*)d_in[4];
  const float* Wv = (const float*)d_in[5];
  const float* bv = (const float*)d_in[6];
  const float* Wo = (const float*)d_in[7];
  const float* bo = (const float*)d_in[8];
  float* out = (float*)d_out;

  char* ws = (char*)d_ws;
  unsigned short* xb    = (unsigned short*)(ws);                      // 8 MB
  unsigned short* wqkvt = (unsigned short*)(ws + (size_t)(8u  << 20)); // 6 MB
  unsigned short* wot   = (unsigned short*)(ws + (size_t)(14u << 20)); // 2 MB
  unsigned short* Qb    = (unsigned short*)(ws + (size_t)(16u << 20)); // 8 MB
  unsigned short* Kb    = (unsigned short*)(ws + (size_t)(24u << 20)); // 8 MB
  unsigned short* Vb    = (unsigned short*)(ws + (size_t)(32u << 20)); // 8 MB
  unsigned short* Vt    = (unsigned short*)(ws + (size_t)(40u << 20)); // 8 MB
  unsigned short* Ocat  = (unsigned short*)(ws + (size_t)(48u << 20)); // 8 MB

  // cast x -> bf16
  k_cast<<<(BB * SS * DD / 4 + 255) / 256, 256, 0, stream>>>(x, xb, BB * SS * DD / 4);
  // transpose-cast weights to [N][K]
  dim3 g1(DHH / 32, DD / 32, HH);
  k_tcast<<<g1, 256, 0, stream>>>(Wq, wqkvt, DD, DHH);
  k_tcast<<<g1, 256, 0, stream>>>(Wk, wqkvt + (size_t)HH * DHH * DD, DD, DHH);
  k_tcast<<<g1, 256, 0, stream>>>(Wv, wqkvt + (size_t)2 * HH * DHH * DD, DD, DHH);
  k_tcast<<<dim3(DD / 32, DD / 32, 1), 256, 0, stream>>>(Wo, wot, DD, DD);
  // QKV projection
  k_qkv<<<dim3(48, 64), 256, 0, stream>>>(xb, wqkvt, bq, bk, bv, Qb, Kb, Vb);
  // V -> Vt (per (b,h): [S][DH] -> [DH][S])
  k_tbf16<<<dim3(DHH / 32, SS / 32, BB * HH), 256, 0, stream>>>(Vb, Vt, SS, DHH);
  // flash attention
  k_attn<<<dim3(SS / 64, BB * HH), 256, 0, stream>>>(Qb, Kb, Vt, Ocat);
  // output projection
  k_proj<<<dim3(DD / 64, 64), 256, 0, stream>>>(Ocat, wot, bo, out);
}

// Round 2
// 159.555 us; speedup vs baseline: 1.4382x; 1.4382x over previous
//
#include <hip/hip_runtime.h>
#include <hip/hip_bf16.h>

#define BB 2
#define SS 2048
#define DD 1024
#define HH 16
#define DHH 64

typedef __attribute__((ext_vector_type(8))) __bf16 bf16x8;
typedef __attribute__((ext_vector_type(4))) float f32x4;
typedef __attribute__((ext_vector_type(16))) float f32x16;
typedef __attribute__((ext_vector_type(4))) int i32x4;
typedef __attribute__((ext_vector_type(4))) unsigned int u32x4;

#define MFMA16 __builtin_amdgcn_mfma_f32_16x16x32_bf16
#define MFMA32 __builtin_amdgcn_mfma_f32_32x32x16_bf16

__device__ __forceinline__ unsigned short f2b(float f) {
  __hip_bfloat16 h = __float2bfloat16(f);
  unsigned short u;
  __builtin_memcpy(&u, &h, 2);
  return u;
}

__device__ __forceinline__ float exp2_fast(float x) {
  float r;
  asm("v_exp_f32 %0, %1" : "=v"(r) : "v"(x));
  return r;
}

__device__ __forceinline__ unsigned int cvtpk_bf16(float lo, float hi) {
  unsigned int r;
  asm("v_cvt_pk_bf16_f32 %0, %1, %2" : "=v"(r) : "v"(lo), "v"(hi));
  return r;
}

// ---------------- cast fp32 -> bf16 (x4 vectorized) ----------------
__global__ __launch_bounds__(256) void k_cast(const float* __restrict__ in,
                                              unsigned short* __restrict__ out, int n4) {
  int i = blockIdx.x * blockDim.x + threadIdx.x;
  if (i >= n4) return;
  float4 v = ((const float4*)in)[i];
  ushort4 o;
  o.x = f2b(v.x); o.y = f2b(v.y); o.z = f2b(v.z); o.w = f2b(v.w);
  ((ushort4*)out)[i] = o;
}

// ------- transpose+cast: per-matrix fp32 [R][C] -> bf16 [C][R] -------
__global__ __launch_bounds__(256) void k_tcast(const float* __restrict__ in,
                                               unsigned short* __restrict__ out, int R, int C) {
  __shared__ float t[32][33];
  size_t mb = (size_t)blockIdx.z * R * C;
  const float* im = in + mb;
  unsigned short* om = out + mb;
  int c0 = blockIdx.x * 32, r0 = blockIdx.y * 32;
  int tx = threadIdx.x & 31, ty = threadIdx.x >> 5;
#pragma unroll
  for (int rr = ty; rr < 32; rr += 8)
    t[rr][tx] = im[(size_t)(r0 + rr) * C + c0 + tx];
  __syncthreads();
#pragma unroll
  for (int rr = ty; rr < 32; rr += 8)
    om[(size_t)(c0 + rr) * R + r0 + tx] = f2b(t[tx][rr]);
}

// ------- transpose bf16: per-matrix [R][C] -> [C][R] -------
__global__ __launch_bounds__(256) void k_tbf16(const unsigned short* __restrict__ in,
                                               unsigned short* __restrict__ out, int R, int C) {
  __shared__ unsigned short t[32][34];
  size_t mb = (size_t)blockIdx.z * R * C;
  const unsigned short* im = in + mb;
  unsigned short* om = out + mb;
  int c0 = blockIdx.x * 32, r0 = blockIdx.y * 32;
  int tx = threadIdx.x & 31, ty = threadIdx.x >> 5;
#pragma unroll
  for (int rr = ty; rr < 32; rr += 8)
    t[rr][tx] = im[(size_t)(r0 + rr) * C + c0 + tx];
  __syncthreads();
#pragma unroll
  for (int rr = ty; rr < 32; rr += 8)
    om[(size_t)(c0 + rr) * R + r0 + tx] = t[tx][rr];
}

// ---------------- QKV GEMM ----------------
// A: xb bf16 [B*S][D].  Wt: [3*H][DH][D] (N-major, K contiguous).
// Q outputs are pre-scaled by 1/sqrt(DH) * log2(e) so attention can use exp2.
__global__ __launch_bounds__(256) void k_qkv(const unsigned short* __restrict__ A,
                                             const unsigned short* __restrict__ Wt,
                                             const float* __restrict__ bq,
                                             const float* __restrict__ bk,
                                             const float* __restrict__ bv,
                                             unsigned short* __restrict__ Qb,
                                             unsigned short* __restrict__ Kb,
                                             unsigned short* __restrict__ Vb) {
  __shared__ __align__(16) unsigned short As[64][72];
  __shared__ __align__(16) unsigned short Bs[64][72];
  int tid = threadIdx.x;
  int w = tid >> 6, lane = tid & 63, lr = lane & 15, lg = lane >> 4;
  int c0 = blockIdx.x * 64;   // 0..3071
  int row0 = blockIdx.y * 64; // 0..4095
  int sel = c0 >> 10;
  int h = (c0 & 1023) >> 6;
  const unsigned short* Bm = Wt + (size_t)(sel * HH + h) * DHH * DD;
  const float* biasp = sel == 0 ? bq : (sel == 1 ? bk : bv);
  unsigned short* outp = sel == 0 ? Qb : (sel == 1 ? Kb : Vb);
  float qscale = sel == 0 ? 0.18033688011112042f : 1.0f;  // 0.125 * log2(e)

  int sr = tid >> 2, se = (tid & 3) * 8;
  const unsigned short* a_src = A + (size_t)(row0 + sr) * DD + se;
  const unsigned short* b_src = Bm + (size_t)sr * DD + se;
  unsigned short* a_dst = &As[sr][se];
  unsigned short* b_dst = &Bs[sr][se];

  f32x4 zero = {0.f, 0.f, 0.f, 0.f};
  f32x4 acc[4];
#pragma unroll
  for (int i = 0; i < 4; i++) acc[i] = zero;

  for (int k0 = 0; k0 < DD; k0 += 64) {
    __syncthreads();
    *(i32x4*)a_dst        = *(const i32x4*)(a_src + k0);
    *(i32x4*)(a_dst + 32) = *(const i32x4*)(a_src + k0 + 32);
    *(i32x4*)b_dst        = *(const i32x4*)(b_src + k0);
    *(i32x4*)(b_dst + 32) = *(const i32x4*)(b_src + k0 + 32);
    __syncthreads();
#pragma unroll
    for (int kk = 0; kk < 2; kk++) {
      bf16x8 af = *(const bf16x8*)&As[16 * w + lr][32 * kk + lg * 8];
#pragma unroll
      for (int cb = 0; cb < 4; cb++) {
        bf16x8 bfr = *(const bf16x8*)&Bs[16 * cb + lr][32 * kk + lg * 8];
        acc[cb] = MFMA16(af, bfr, acc[cb], 0, 0, 0);
      }
    }
  }
#pragma unroll
  for (int cb = 0; cb < 4; cb++) {
    int d = 16 * cb + lr;
    float bias = biasp[h * DHH + d];
#pragma unroll
    for (int r = 0; r < 4; r++) {
      int grow = row0 + 16 * w + lg * 4 + r;
      int b = grow >> 11, s = grow & 2047;
      outp[((size_t)(b * HH + h) * SS + s) * DHH + d] = f2b((acc[cb][r] + bias) * qscale);
    }
  }
}

// ---------------- output projection GEMM ----------------
__global__ __launch_bounds__(256) void k_proj(const unsigned short* __restrict__ A,
                                              const unsigned short* __restrict__ Wt,
                                              const float* __restrict__ bo,
                                              float* __restrict__ out) {
  __shared__ __align__(16) unsigned short As[64][72];
  __shared__ __align__(16) unsigned short Bs[64][72];
  int tid = threadIdx.x;
  int w = tid >> 6, lane = tid & 63, lr = lane & 15, lg = lane >> 4;
  int c0 = blockIdx.x * 64;
  int row0 = blockIdx.y * 64;

  int sr = tid >> 2, se = (tid & 3) * 8;
  const unsigned short* a_src = A + (size_t)(row0 + sr) * DD + se;
  const unsigned short* b_src = Wt + (size_t)(c0 + sr) * DD + se;
  unsigned short* a_dst = &As[sr][se];
  unsigned short* b_dst = &Bs[sr][se];

  f32x4 zero = {0.f, 0.f, 0.f, 0.f};
  f32x4 acc[4];
#pragma unroll
  for (int i = 0; i < 4; i++) acc[i] = zero;

  for (int k0 = 0; k0 < DD; k0 += 64) {
    __syncthreads();
    *(i32x4*)a_dst        = *(const i32x4*)(a_src + k0);
    *(i32x4*)(a_dst + 32) = *(const i32x4*)(a_src + k0 + 32);
    *(i32x4*)b_dst        = *(const i32x4*)(b_src + k0);
    *(i32x4*)(b_dst + 32) = *(const i32x4*)(b_src + k0 + 32);
    __syncthreads();
#pragma unroll
    for (int kk = 0; kk < 2; kk++) {
      bf16x8 af = *(const bf16x8*)&As[16 * w + lr][32 * kk + lg * 8];
#pragma unroll
      for (int cb = 0; cb < 4; cb++) {
        bf16x8 bfr = *(const bf16x8*)&Bs[16 * cb + lr][32 * kk + lg * 8];
        acc[cb] = MFMA16(af, bfr, acc[cb], 0, 0, 0);
      }
    }
  }
#pragma unroll
  for (int cb = 0; cb < 4; cb++) {
    int c = c0 + 16 * cb + lr;
    float bias = bo[c];
#pragma unroll
    for (int r = 0; r < 4; r++) {
      int grow = row0 + 16 * w + lg * 4 + r;
      out[(size_t)grow * DD + c] = acc[cb][r] + bias;
    }
  }
}

// ---------------- flash attention (swapped-operand, 32x32 MFMA) ----------------
// Q (pre-scaled by 0.125*log2e), K: [B*H][S][DH] bf16. Vt: [B*H][DH][S] bf16.
// Ocat: [B][S][H*DH] bf16.
// Block: 512 thr = 8 warps; each warp owns 32 q rows; KV tile = 64.
// QK^T as mfma(K, Q) -> D[kv][q], q = lane&31 (softmax lane-local).
// PV  as mfma(Vt, P) -> D[d][q], same q-per-lane form.
#define QT 256
#define KVB 64

__global__ __launch_bounds__(512, 2) void k_attn(const unsigned short* __restrict__ Q,
                                                 const unsigned short* __restrict__ K,
                                                 const unsigned short* __restrict__ Vt,
                                                 unsigned short* __restrict__ Ocat) {
  // Qs[256][64] (32KB, swizzled, stride 128B) reused as Os[256][72] (36KB) at end.
  __shared__ __align__(16) char sm[36864 + 8192 + 8192];
  unsigned short* Qs = (unsigned short*)sm;
  char* Ksb = sm + 36864;
  char* Vsb = sm + 45056;

  int tid = threadIdx.x;
  int w = tid >> 6;
  int lane = tid & 63;
  int q32 = lane & 31;
  int hi = lane >> 5;
  bool lo = (hi == 0);
  int bh = blockIdx.y;
  int bi = bh >> 4, h = bh & 15;
  int q0 = blockIdx.x * QT;
  const unsigned short* Qm = Q + (size_t)bh * SS * DHH;
  const unsigned short* Km = K + (size_t)bh * SS * DHH;
  const unsigned short* Vm = Vt + (size_t)bh * DHH * SS;

  // ---- stage Q once (2048 x 16B chunks, XOR-swizzled rows) ----
#pragma unroll
  for (int i = 0; i < 4; i++) {
    int ci = tid + i * 512;
    int r = ci >> 3, c = ci & 7;
    i32x4 v = *(const i32x4*)(Qm + (size_t)(q0 + r) * DHH + c * 8);
    *(i32x4*)((char*)Qs + r * 128 + ((c * 16) ^ ((r & 7) << 4))) = v;
  }
  __syncthreads();

  // ---- hoist Q fragments (B-operand): row = warp's q, col = dh slice ----
  bf16x8 qf[4];
  {
    int r = w * 32 + q32;
    const char* base = (const char*)Qs + r * 128;
    int sw = (r & 7) << 4;
#pragma unroll
    for (int ks = 0; ks < 4; ks++)
      qf[ks] = *(const bf16x8*)(base + ((ks * 32 + hi * 16) ^ sw));
  }

  f32x16 oacc0 = {}, oacc1 = {};
  float m_ = -1e30f, l_ = 0.f;

  // staging thread mapping: row = tid>>3 (0..63), chunk = tid&7
  int srow = tid >> 3, sc = tid & 7;
  char* kdst = Ksb + srow * 128 + (((sc * 16) ^ ((srow & 7) << 4)));
  char* vdst = Vsb + srow * 128 + (((sc * 16) ^ ((srow & 7) << 4)));
  const int swq = (q32 & 7) << 4;

  // prefetch tile 0 into regs (T14 split: issue-early / write-late)
  i32x4 kreg = *(const i32x4*)(Km + (size_t)srow * DHH + sc * 8);
  i32x4 vreg = *(const i32x4*)(Vm + (size_t)srow * SS + 0 + sc * 8);

  for (int kv0 = 0; kv0 < SS; kv0 += KVB) {
    __syncthreads();  // previous tile's LDS reads done
    *(i32x4*)kdst = kreg;
    *(i32x4*)vdst = vreg;
    __syncthreads();  // tile staged
    if (kv0 + KVB < SS) {  // issue next-tile loads; consumed next iteration
      kreg = *(const i32x4*)(Km + (size_t)(kv0 + KVB + srow) * DHH + sc * 8);
      vreg = *(const i32x4*)(Vm + (size_t)srow * SS + (kv0 + KVB) + sc * 8);
    }

    // ---- QK^T: pacc[b] = K[32b..32b+31] x Q^T  -> D[kv][q] ----
    f32x16 pacc0 = {}, pacc1 = {};
#pragma unroll
    for (int ks = 0; ks < 4; ks++) {
      bf16x8 kf0 = *(const bf16x8*)(Ksb + q32 * 128 + ((ks * 32 + hi * 16) ^ swq));
      bf16x8 kf1 = *(const bf16x8*)(Ksb + (32 + q32) * 128 + ((ks * 32 + hi * 16) ^ swq));
      pacc0 = MFMA32(kf0, qf[ks], pacc0, 0, 0, 0);
      pacc1 = MFMA32(kf1, qf[ks], pacc1, 0, 0, 0);
    }

    // ---- online softmax (lane-local row; values already in log2 units) ----
    float t_ = pacc0[0];
#pragma unroll
    for (int r = 1; r < 16; r++) t_ = fmaxf(t_, pacc0[r]);
#pragma unroll
    for (int r = 0; r < 16; r++) t_ = fmaxf(t_, pacc1[r]);
    t_ = fmaxf(t_, __shfl_xor(t_, 32));

    if (__any(t_ > m_ + 8.0f)) {  // defer-max: skip rescale when growth small
      float nm = fmaxf(m_, t_);
      float al = exp2_fast(m_ - nm);
      m_ = nm;
      l_ *= al;
#pragma unroll
      for (int r = 0; r < 16; r++) { oacc0[r] *= al; oacc1[r] *= al; }
    }

    float s_ = 0.f;
#pragma unroll
    for (int r = 0; r < 16; r++) { pacc0[r] = exp2_fast(pacc0[r] - m_); s_ += pacc0[r]; }
#pragma unroll
    for (int r = 0; r < 16; r++) { pacc1[r] = exp2_fast(pacc1[r] - m_); s_ += pacc1[r]; }
    s_ += __shfl_xor(s_, 32);
    l_ += s_;

    // ---- P -> bf16 A/B-fragment form: pa[s] elem (hi,j) = P[16s+8hi+j][q] ----
    u32x4 pa[4];
#pragma unroll
    for (int b2 = 0; b2 < 2; b2++) {
#pragma unroll
      for (int u = 0; u < 2; u++) {
        float p0, p1, p2, p3, p4, p5, p6, p7;
        if (b2 == 0) {
          p0 = pacc0[8*u+0]; p1 = pacc0[8*u+1]; p2 = pacc0[8*u+2]; p3 = pacc0[8*u+3];
          p4 = pacc0[8*u+4]; p5 = pacc0[8*u+5]; p6 = pacc0[8*u+6]; p7 = pacc0[8*u+7];
        } else {
          p0 = pacc1[8*u+0]; p1 = pacc1[8*u+1]; p2 = pacc1[8*u+2]; p3 = pacc1[8*u+3];
          p4 = pacc1[8*u+4]; p5 = pacc1[8*u+5]; p6 = pacc1[8*u+6]; p7 = pacc1[8*u+7];
        }
        unsigned int x0 = cvtpk_bf16(p0, p1), x1 = cvtpk_bf16(p2, p3);
        unsigned int y0 = cvtpk_bf16(p4, p5), y1 = cvtpk_bf16(p6, p7);
        unsigned int sx0 = (unsigned int)__shfl_xor((int)x0, 32);
        unsigned int sx1 = (unsigned int)__shfl_xor((int)x1, 32);
        unsigned int sy0 = (unsigned int)__shfl_xor((int)y0, 32);
        unsigned int sy1 = (unsigned int)__shfl_xor((int)y1, 32);
        int s = 2 * b2 + u;
        pa[s][0] = lo ? x0 : sy0;
        pa[s][1] = lo ? x1 : sy1;
        pa[s][2] = lo ? sx0 : y0;
        pa[s][3] = lo ? sx1 : y1;
      }
    }

    // ---- PV: oacc[db] += Vt[d-block] x P -> D[d][q] ----
#pragma unroll
    for (int db = 0; db < 2; db++) {
      const char* vb = Vsb + (db * 32 + q32) * 128;
#pragma unroll
      for (int s = 0; s < 4; s++) {
        bf16x8 vf = *(const bf16x8*)(vb + ((s * 32 + hi * 16) ^ swq));
        bf16x8 pf = *(const bf16x8*)&pa[s];
        if (db == 0) oacc0 = MFMA32(vf, pf, oacc0, 0, 0, 0);
        else         oacc1 = MFMA32(vf, pf, oacc1, 0, 0, 0);
      }
    }
  }

  // ---- epilogue: normalize, transpose via LDS (reuse Q region), coalesced store ----
  __syncthreads();
  float inv = 1.0f / l_;
  unsigned short* Os = (unsigned short*)sm;  // [256][72]
  int rowq = w * 32 + q32;
#pragma unroll
  for (int db = 0; db < 2; db++) {
#pragma unroll
    for (int r = 0; r < 16; r++) {
      int d = db * 32 + (r & 3) + 8 * (r >> 2) + 4 * hi;
      float v = (db == 0 ? oacc0[r] : oacc1[r]) * inv;
      Os[rowq * 72 + d] = f2b(v);
    }
  }
  __syncthreads();
#pragma unroll
  for (int i = 0; i < 4; i++) {
    int ci = tid + i * 512;
    int r = ci >> 3, c = ci & 7;
    i32x4 v = *(const i32x4*)(Os + r * 72 + c * 8);
    *(i32x4*)(Ocat + ((size_t)(bi * SS + q0 + r)) * DD + h * DHH + c * 8) = v;
  }
}

extern "C" void kernel_launch(void* const* d_in, const int* in_sizes, int n_in,
                              void* d_out, int out_size, void* d_ws, size_t ws_size,
                              hipStream_t stream) {
  const float* x  = (const float*)d_in[0];
  const float* Wq = (const float*)d_in[1];
  const float* bq = (const float*)d_in[2];
  const float* Wk = (const float*)d_in[3];
  const float* bk = (const float*)d_in[4];
  const float* Wv = (const float*)d_in[5];
  const float* bv = (const float*)d_in[6];
  const float* Wo = (const float*)d_in[7];
  const float* bo = (const float*)d_in[8];
  float* out = (float*)d_out;

  char* ws = (char*)d_ws;
  unsigned short* xb    = (unsigned short*)(ws);                       // 8 MB
  unsigned short* wqkvt = (unsigned short*)(ws + (size_t)(8u  << 20)); // 6 MB
  unsigned short* wot   = (unsigned short*)(ws + (size_t)(14u << 20)); // 2 MB
  unsigned short* Qb    = (unsigned short*)(ws + (size_t)(16u << 20)); // 8 MB
  unsigned short* Kb    = (unsigned short*)(ws + (size_t)(24u << 20)); // 8 MB
  unsigned short* Vb    = (unsigned short*)(ws + (size_t)(32u << 20)); // 8 MB
  unsigned short* Vt    = (unsigned short*)(ws + (size_t)(40u << 20)); // 8 MB
  unsigned short* Ocat  = (unsigned short*)(ws + (size_t)(48u << 20)); // 8 MB

  k_cast<<<(BB * SS * DD / 4 + 255) / 256, 256, 0, stream>>>(x, xb, BB * SS * DD / 4);
  dim3 g1(DHH / 32, DD / 32, HH);
  k_tcast<<<g1, 256, 0, stream>>>(Wq, wqkvt, DD, DHH);
  k_tcast<<<g1, 256, 0, stream>>>(Wk, wqkvt + (size_t)HH * DHH * DD, DD, DHH);
  k_tcast<<<g1, 256, 0, stream>>>(Wv, wqkvt + (size_t)2 * HH * DHH * DD, DD, DHH);
  k_tcast<<<dim3(DD / 32, DD / 32, 1), 256, 0, stream>>>(Wo, wot, DD, DD);
  k_qkv<<<dim3(48, 64), 256, 0, stream>>>(xb, wqkvt, bq, bk, bv, Qb, Kb, Vb);
  k_tbf16<<<dim3(DHH / 32, SS / 32, BB * HH), 256, 0, stream>>>(Vb, Vt, SS, DHH);
  k_attn<<<dim3(SS / QT, BB * HH), 512, 0, stream>>>(Qb, Kb, Vt, Ocat);
  k_proj<<<dim3(DD / 64, 64), 256, 0, stream>>>(Ocat, wot, bo, out);
}

// Round 3
// 152.288 us; speedup vs baseline: 1.5069x; 1.0477x over previous
//
#include <hip/hip_runtime.h>
#include <hip/hip_bf16.h>

#define BB 2
#define SS 2048
#define DD 1024
#define HH 16
#define DHH 64

typedef __attribute__((ext_vector_type(8))) __bf16 bf16x8;
typedef __attribute__((ext_vector_type(4))) float f32x4;
typedef __attribute__((ext_vector_type(16))) float f32x16;
typedef __attribute__((ext_vector_type(4))) int i32x4;
typedef __attribute__((ext_vector_type(4))) unsigned int u32x4;

#define MFMA16 __builtin_amdgcn_mfma_f32_16x16x32_bf16
#define MFMA32 __builtin_amdgcn_mfma_f32_32x32x16_bf16

__device__ __forceinline__ unsigned short f2b(float f) {
  __hip_bfloat16 h = __float2bfloat16(f);
  unsigned short u;
  __builtin_memcpy(&u, &h, 2);
  return u;
}

__device__ __forceinline__ float exp2_fast(float x) {
  float r;
  asm("v_exp_f32 %0, %1" : "=v"(r) : "v"(x));
  return r;
}

__device__ __forceinline__ unsigned int cvtpk_bf16(float lo, float hi) {
  unsigned int r;
  asm("v_cvt_pk_bf16_f32 %0, %1, %2" : "=v"(r) : "v"(lo), "v"(hi));
  return r;
}

// async global -> LDS, 16B per lane. LDS dest = wave-uniform base + lane*16.
__device__ __forceinline__ void gl_lds16(const void* g, void* l) {
  __builtin_amdgcn_global_load_lds((const __attribute__((address_space(1))) void*)g,
                                   (__attribute__((address_space(3))) void*)l, 16, 0, 0);
}

// ---------------- cast fp32 -> bf16 (x4 vectorized) ----------------
__global__ __launch_bounds__(256) void k_cast(const float* __restrict__ in,
                                              unsigned short* __restrict__ out, int n4) {
  int i = blockIdx.x * blockDim.x + threadIdx.x;
  if (i >= n4) return;
  float4 v = ((const float4*)in)[i];
  ushort4 o;
  o.x = f2b(v.x); o.y = f2b(v.y); o.z = f2b(v.z); o.w = f2b(v.w);
  ((ushort4*)out)[i] = o;
}

// ------- transpose+cast: per-matrix fp32 [R][C] -> bf16 [C][R] -------
__global__ __launch_bounds__(256) void k_tcast(const float* __restrict__ in,
                                               unsigned short* __restrict__ out, int R, int C) {
  __shared__ float t[32][33];
  size_t mb = (size_t)blockIdx.z * R * C;
  const float* im = in + mb;
  unsigned short* om = out + mb;
  int c0 = blockIdx.x * 32, r0 = blockIdx.y * 32;
  int tx = threadIdx.x & 31, ty = threadIdx.x >> 5;
#pragma unroll
  for (int rr = ty; rr < 32; rr += 8)
    t[rr][tx] = im[(size_t)(r0 + rr) * C + c0 + tx];
  __syncthreads();
#pragma unroll
  for (int rr = ty; rr < 32; rr += 8)
    om[(size_t)(c0 + rr) * R + r0 + tx] = f2b(t[tx][rr]);
}

// ------- transpose bf16: per-matrix [R][C] -> [C][R] -------
__global__ __launch_bounds__(256) void k_tbf16(const unsigned short* __restrict__ in,
                                               unsigned short* __restrict__ out, int R, int C) {
  __shared__ unsigned short t[32][34];
  size_t mb = (size_t)blockIdx.z * R * C;
  const unsigned short* im = in + mb;
  unsigned short* om = out + mb;
  int c0 = blockIdx.x * 32, r0 = blockIdx.y * 32;
  int tx = threadIdx.x & 31, ty = threadIdx.x >> 5;
#pragma unroll
  for (int rr = ty; rr < 32; rr += 8)
    t[rr][tx] = im[(size_t)(r0 + rr) * C + c0 + tx];
  __syncthreads();
#pragma unroll
  for (int rr = ty; rr < 32; rr += 8)
    om[(size_t)(c0 + rr) * R + r0 + tx] = t[tx][rr];
}

// ---------------- QKV GEMM: 128x128 tile, BK=64, global_load_lds ----------------
// A: xb bf16 [4096][1024]. Wt: [3072][1024] (N-major, K contiguous).
// Q outputs pre-scaled by 1/sqrt(DH)*log2(e) so attention uses exp2 directly.
__global__ __launch_bounds__(256) void k_qkv(const unsigned short* __restrict__ A,
                                             const unsigned short* __restrict__ Wt,
                                             const float* __restrict__ bq,
                                             const float* __restrict__ bk,
                                             const float* __restrict__ bv,
                                             unsigned short* __restrict__ Qb,
                                             unsigned short* __restrict__ Kb,
                                             unsigned short* __restrict__ Vb) {
  __shared__ __align__(16) unsigned short As[128 * 64];
  __shared__ __align__(16) unsigned short Bs[128 * 64];
  int tid = threadIdx.x;
  int w = tid >> 6, l = tid & 63, lr = l & 15, lg = l >> 4;
  int wr = w >> 1, wc = w & 1;
  int col0 = blockIdx.x * 128, row0 = blockIdx.y * 128;
  int sel = col0 >> 10;
  const float* biasp = sel == 0 ? bq : (sel == 1 ? bk : bv);
  unsigned short* outp = sel == 0 ? Qb : (sel == 1 ? Kb : Vb);
  float qscale = sel == 0 ? 0.18033688011112042f : 1.0f;  // 0.125 * log2(e)

  int r8 = l >> 3, c8 = l & 7;
  const unsigned short* Ab = A + (size_t)(row0 + w * 32 + r8) * DD + c8 * 8;
  const unsigned short* Bb = Wt + (size_t)(col0 + w * 32 + r8) * DD + c8 * 8;

  f32x4 zero = {0.f, 0.f, 0.f, 0.f};
  f32x4 acc[4][4];
#pragma unroll
  for (int m = 0; m < 4; m++)
#pragma unroll
    for (int n = 0; n < 4; n++) acc[m][n] = zero;

  for (int k0 = 0; k0 < DD; k0 += 64) {
    __syncthreads();
#pragma unroll
    for (int c = 0; c < 4; c++) {
      gl_lds16(Ab + (size_t)c * 8 * DD + k0, (char*)As + (w * 32 + c * 8) * 128);
      gl_lds16(Bb + (size_t)c * 8 * DD + k0, (char*)Bs + (w * 32 + c * 8) * 128);
    }
    __syncthreads();
#pragma unroll
    for (int kk = 0; kk < 2; kk++) {
      bf16x8 af[4], bfr[4];
#pragma unroll
      for (int m = 0; m < 4; m++)
        af[m] = *(const bf16x8*)&As[(wr * 64 + m * 16 + lr) * 64 + kk * 32 + lg * 8];
#pragma unroll
      for (int n = 0; n < 4; n++)
        bfr[n] = *(const bf16x8*)&Bs[(wc * 64 + n * 16 + lr) * 64 + kk * 32 + lg * 8];
#pragma unroll
      for (int m = 0; m < 4; m++)
#pragma unroll
        for (int n = 0; n < 4; n++)
          acc[m][n] = MFMA16(af[m], bfr[n], acc[m][n], 0, 0, 0);
    }
  }

#pragma unroll
  for (int n = 0; n < 4; n++) {
    int c = col0 + wc * 64 + n * 16 + lr;
    int h = (c >> 6) & 15;
    int d = c & 63;
    float bias = biasp[h * DHH + d];
#pragma unroll
    for (int m = 0; m < 4; m++) {
#pragma unroll
      for (int j = 0; j < 4; j++) {
        int row = row0 + wr * 64 + m * 16 + lg * 4 + j;
        int b = row >> 11, s = row & 2047;
        outp[((size_t)(b * HH + h) * SS + s) * DHH + d] = f2b((acc[m][n][j] + bias) * qscale);
      }
    }
  }
}

// ---------------- output projection GEMM: 128x128 tile ----------------
__global__ __launch_bounds__(256) void k_proj(const unsigned short* __restrict__ A,
                                              const unsigned short* __restrict__ Wt,
                                              const float* __restrict__ bo,
                                              float* __restrict__ out) {
  __shared__ __align__(16) unsigned short As[128 * 64];
  __shared__ __align__(16) unsigned short Bs[128 * 64];
  int tid = threadIdx.x;
  int w = tid >> 6, l = tid & 63, lr = l & 15, lg = l >> 4;
  int wr = w >> 1, wc = w & 1;
  int col0 = blockIdx.x * 128, row0 = blockIdx.y * 128;

  int r8 = l >> 3, c8 = l & 7;
  const unsigned short* Ab = A + (size_t)(row0 + w * 32 + r8) * DD + c8 * 8;
  const unsigned short* Bb = Wt + (size_t)(col0 + w * 32 + r8) * DD + c8 * 8;

  f32x4 zero = {0.f, 0.f, 0.f, 0.f};
  f32x4 acc[4][4];
#pragma unroll
  for (int m = 0; m < 4; m++)
#pragma unroll
    for (int n = 0; n < 4; n++) acc[m][n] = zero;

  for (int k0 = 0; k0 < DD; k0 += 64) {
    __syncthreads();
#pragma unroll
    for (int c = 0; c < 4; c++) {
      gl_lds16(Ab + (size_t)c * 8 * DD + k0, (char*)As + (w * 32 + c * 8) * 128);
      gl_lds16(Bb + (size_t)c * 8 * DD + k0, (char*)Bs + (w * 32 + c * 8) * 128);
    }
    __syncthreads();
#pragma unroll
    for (int kk = 0; kk < 2; kk++) {
      bf16x8 af[4], bfr[4];
#pragma unroll
      for (int m = 0; m < 4; m++)
        af[m] = *(const bf16x8*)&As[(wr * 64 + m * 16 + lr) * 64 + kk * 32 + lg * 8];
#pragma unroll
      for (int n = 0; n < 4; n++)
        bfr[n] = *(const bf16x8*)&Bs[(wc * 64 + n * 16 + lr) * 64 + kk * 32 + lg * 8];
#pragma unroll
      for (int m = 0; m < 4; m++)
#pragma unroll
        for (int n = 0; n < 4; n++)
          acc[m][n] = MFMA16(af[m], bfr[n], acc[m][n], 0, 0, 0);
    }
  }

#pragma unroll
  for (int n = 0; n < 4; n++) {
    int c = col0 + wc * 64 + n * 16 + lr;
    float bias = bo[c];
#pragma unroll
    for (int m = 0; m < 4; m++) {
#pragma unroll
      for (int j = 0; j < 4; j++) {
        int row = row0 + wr * 64 + m * 16 + lg * 4 + j;
        out[(size_t)row * DD + c] = acc[m][n][j] + bias;
      }
    }
  }
}

// ---------------- flash attention ----------------
// QT=128 q-rows/block, 4 warps (32 q-rows each), KVB=64, K/V double-buffered.
// Staging = global_load_lds with pre-swizzled GLOBAL src (LDS linear write);
// reads XOR-deswizzle. One barrier per tile. XCD-aware block swizzle.
#define QT 128
#define KVB 64

__global__ __launch_bounds__(256, 3) void k_attn(const unsigned short* __restrict__ Q,
                                                 const unsigned short* __restrict__ K,
                                                 const unsigned short* __restrict__ Vt,
                                                 unsigned short* __restrict__ Ocat) {
  // [0,18432): Qs (swizzled [128] rows x 128B), reused as Os[128][72] in epilogue.
  // [18432, 34816): K double buffer (2 x 8KB). [34816, 51200): V double buffer.
  __shared__ __align__(16) char sm[51200];
  unsigned short* Qs = (unsigned short*)sm;

  int tid = threadIdx.x;
  int w = tid >> 6;
  int lane = tid & 63;
  int q32 = lane & 31;
  int hi = lane >> 5;
  bool lo = (hi == 0);
  int r8 = lane >> 3, c8 = lane & 7;

  // XCD-aware swizzle: all 16 q-tiles of one (b,h) land on one XCD (bijective).
  int n = blockIdx.x;
  int bh = ((n & 7) << 2) | ((n >> 3) & 3);
  int q0 = (n >> 5) * QT;
  int bi = bh >> 4, h = bh & 15;
  const unsigned short* Qm = Q + (size_t)bh * SS * DHH;
  const unsigned short* Km = K + (size_t)bh * SS * DHH;
  const unsigned short* Vm = Vt + (size_t)bh * DHH * SS;

  // ---- stage Q (async DMA, pre-swizzled source) ----
#pragma unroll
  for (int c = 0; c < 4; c++) {
    int rQ = w * 32 + c * 8 + r8;
    int cg = c8 ^ (rQ & 7);
    gl_lds16(Qm + (size_t)(q0 + rQ) * DHH + cg * 8, sm + (w * 32 + c * 8) * 128);
  }
  // ---- stage K/V tile 0 into buffer 0 ----
#pragma unroll
  for (int c = 0; c < 2; c++) {
    int rr = w * 16 + c * 8 + r8;
    int cg = c8 ^ (rr & 7);
    gl_lds16(Km + (size_t)rr * DHH + cg * 8, sm + 18432 + (w * 16 + c * 8) * 128);
    gl_lds16(Vm + (size_t)rr * SS + cg * 8, sm + 34816 + (w * 16 + c * 8) * 128);
  }
  __syncthreads();  // drains vmcnt: Q + tile0 ready

  // ---- hoist Q fragments (B-operand) ----
  bf16x8 qf[4];
  {
    int r = w * 32 + q32;
    const char* base = (const char*)Qs + r * 128;
    int sw = (r & 7) << 4;
#pragma unroll
    for (int ks = 0; ks < 4; ks++)
      qf[ks] = *(const bf16x8*)(base + ((ks * 32 + hi * 16) ^ sw));
  }

  f32x16 oacc0 = {}, oacc1 = {};
  float m_ = -1e30f, l_ = 0.f;
  const int swq = (q32 & 7) << 4;

  for (int t = 0; t < SS / KVB; t++) {
    int cur = t & 1;
    const char* Ksb = sm + 18432 + cur * 8192;
    const char* Vsb = sm + 34816 + cur * 8192;

    // issue next tile's async DMA into the other buffer (readers done at t-1)
    if (t + 1 < SS / KVB) {
      int kv0 = (t + 1) * KVB;
      char* kdst = sm + 18432 + (cur ^ 1) * 8192;
      char* vdst = sm + 34816 + (cur ^ 1) * 8192;
#pragma unroll
      for (int c = 0; c < 2; c++) {
        int rr = w * 16 + c * 8 + r8;
        int cg = c8 ^ (rr & 7);
        gl_lds16(Km + (size_t)(kv0 + rr) * DHH + cg * 8, kdst + (w * 16 + c * 8) * 128);
        gl_lds16(Vm + (size_t)rr * SS + kv0 + cg * 8, vdst + (w * 16 + c * 8) * 128);
      }
    }

    // ---- QK^T: mfma(K, Q) -> D[kv][q], q = lane&31 ----
    f32x16 pacc0 = {}, pacc1 = {};
    __builtin_amdgcn_s_setprio(1);
#pragma unroll
    for (int ks = 0; ks < 4; ks++) {
      bf16x8 kf0 = *(const bf16x8*)(Ksb + q32 * 128 + ((ks * 32 + hi * 16) ^ swq));
      bf16x8 kf1 = *(const bf16x8*)(Ksb + (32 + q32) * 128 + ((ks * 32 + hi * 16) ^ swq));
      pacc0 = MFMA32(kf0, qf[ks], pacc0, 0, 0, 0);
      pacc1 = MFMA32(kf1, qf[ks], pacc1, 0, 0, 0);
    }
    __builtin_amdgcn_s_setprio(0);

    // ---- online softmax (lane-local rows; log2 units) ----
    float t_ = pacc0[0];
#pragma unroll
    for (int r = 1; r < 16; r++) t_ = fmaxf(t_, pacc0[r]);
#pragma unroll
    for (int r = 0; r < 16; r++) t_ = fmaxf(t_, pacc1[r]);
    t_ = fmaxf(t_, __shfl_xor(t_, 32));

    if (__any(t_ > m_ + 8.0f)) {  // defer-max
      float nm = fmaxf(m_, t_);
      float al = exp2_fast(m_ - nm);
      m_ = nm;
      l_ *= al;
#pragma unroll
      for (int r = 0; r < 16; r++) { oacc0[r] *= al; oacc1[r] *= al; }
    }

    float s_ = 0.f;
#pragma unroll
    for (int r = 0; r < 16; r++) { pacc0[r] = exp2_fast(pacc0[r] - m_); s_ += pacc0[r]; }
#pragma unroll
    for (int r = 0; r < 16; r++) { pacc1[r] = exp2_fast(pacc1[r] - m_); s_ += pacc1[r]; }
    s_ += __shfl_xor(s_, 32);
    l_ += s_;

    // ---- P -> bf16 A-fragment form ----
    u32x4 pa[4];
#pragma unroll
    for (int b2 = 0; b2 < 2; b2++) {
#pragma unroll
      for (int u = 0; u < 2; u++) {
        float p0, p1, p2, p3, p4, p5, p6, p7;
        if (b2 == 0) {
          p0 = pacc0[8*u+0]; p1 = pacc0[8*u+1]; p2 = pacc0[8*u+2]; p3 = pacc0[8*u+3];
          p4 = pacc0[8*u+4]; p5 = pacc0[8*u+5]; p6 = pacc0[8*u+6]; p7 = pacc0[8*u+7];
        } else {
          p0 = pacc1[8*u+0]; p1 = pacc1[8*u+1]; p2 = pacc1[8*u+2]; p3 = pacc1[8*u+3];
          p4 = pacc1[8*u+4]; p5 = pacc1[8*u+5]; p6 = pacc1[8*u+6]; p7 = pacc1[8*u+7];
        }
        unsigned int x0 = cvtpk_bf16(p0, p1), x1 = cvtpk_bf16(p2, p3);
        unsigned int y0 = cvtpk_bf16(p4, p5), y1 = cvtpk_bf16(p6, p7);
        unsigned int sx0 = (unsigned int)__shfl_xor((int)x0, 32);
        unsigned int sx1 = (unsigned int)__shfl_xor((int)x1, 32);
        unsigned int sy0 = (unsigned int)__shfl_xor((int)y0, 32);
        unsigned int sy1 = (unsigned int)__shfl_xor((int)y1, 32);
        int s = 2 * b2 + u;
        pa[s][0] = lo ? x0 : sy0;
        pa[s][1] = lo ? x1 : sy1;
        pa[s][2] = lo ? sx0 : y0;
        pa[s][3] = lo ? sx1 : y1;
      }
    }

    // ---- PV: mfma(Vt, P) -> D[d][q] ----
    __builtin_amdgcn_s_setprio(1);
#pragma unroll
    for (int db = 0; db < 2; db++) {
      const char* vb = Vsb + (db * 32 + q32) * 128;
#pragma unroll
      for (int s = 0; s < 4; s++) {
        bf16x8 vf = *(const bf16x8*)(vb + ((s * 32 + hi * 16) ^ swq));
        bf16x8 pf = *(const bf16x8*)&pa[s];
        if (db == 0) oacc0 = MFMA32(vf, pf, oacc0, 0, 0, 0);
        else         oacc1 = MFMA32(vf, pf, oacc1, 0, 0, 0);
      }
    }
    __builtin_amdgcn_s_setprio(0);

    __syncthreads();  // drains next-tile DMA + separates buffer reuse
  }

  // ---- epilogue: normalize, transpose via LDS (reuse Q region), coalesced store ----
  float inv = 1.0f / l_;
  unsigned short* Os = (unsigned short*)sm;  // [128][72]
  int rowq = w * 32 + q32;
#pragma unroll
  for (int db = 0; db < 2; db++) {
#pragma unroll
    for (int r = 0; r < 16; r++) {
      int d = db * 32 + (r & 3) + 8 * (r >> 2) + 4 * hi;
      float v = (db == 0 ? oacc0[r] : oacc1[r]) * inv;
      Os[rowq * 72 + d] = f2b(v);
    }
  }
  __syncthreads();
#pragma unroll
  for (int i = 0; i < 4; i++) {
    int ci = tid + i * 256;
    int r = ci >> 3, c = ci & 7;
    i32x4 v = *(const i32x4*)(Os + r * 72 + c * 8);
    *(i32x4*)(Ocat + ((size_t)(bi * SS + q0 + r)) * DD + h * DHH + c * 8) = v;
  }
}

extern "C" void kernel_launch(void* const* d_in, const int* in_sizes, int n_in,
                              void* d_out, int out_size, void* d_ws, size_t ws_size,
                              hipStream_t stream) {
  const float* x  = (const float*)d_in[0];
  const float* Wq = (const float*)d_in[1];
  const float* bq = (const float*)d_in[2];
  const float* Wk = (const float*)d_in[3];
  const float* bk = (const float*)d_in[4];
  const float* Wv = (const float*)d_in[5];
  const float* bv = (const float*)d_in[6];
  const float* Wo = (const float*)d_in[7];
  const float* bo = (const float*)d_in[8];
  float* out = (float*)d_out;

  char* ws = (char*)d_ws;
  unsigned short* xb    = (unsigned short*)(ws);                       // 8 MB
  unsigned short* wqkvt = (unsigned short*)(ws + (size_t)(8u  << 20)); // 6 MB
  unsigned short* wot   = (unsigned short*)(ws + (size_t)(14u << 20)); // 2 MB
  unsigned short* Qb    = (unsigned short*)(ws + (size_t)(16u << 20)); // 8 MB
  unsigned short* Kb    = (unsigned short*)(ws + (size_t)(24u << 20)); // 8 MB
  unsigned short* Vb    = (unsigned short*)(ws + (size_t)(32u << 20)); // 8 MB
  unsigned short* Vt    = (unsigned short*)(ws + (size_t)(40u << 20)); // 8 MB
  unsigned short* Ocat  = (unsigned short*)(ws + (size_t)(48u << 20)); // 8 MB

  k_cast<<<(BB * SS * DD / 4 + 255) / 256, 256, 0, stream>>>(x, xb, BB * SS * DD / 4);
  dim3 g1(DHH / 32, DD / 32, HH);
  k_tcast<<<g1, 256, 0, stream>>>(Wq, wqkvt, DD, DHH);
  k_tcast<<<g1, 256, 0, stream>>>(Wk, wqkvt + (size_t)HH * DHH * DD, DD, DHH);
  k_tcast<<<g1, 256, 0, stream>>>(Wv, wqkvt + (size_t)2 * HH * DHH * DD, DD, DHH);
  k_tcast<<<dim3(DD / 32, DD / 32, 1), 256, 0, stream>>>(Wo, wot, DD, DD);
  k_qkv<<<dim3(3 * DD / 128, BB * SS / 128), 256, 0, stream>>>(xb, wqkvt, bq, bk, bv, Qb, Kb, Vb);
  k_tbf16<<<dim3(DHH / 32, SS / 32, BB * HH), 256, 0, stream>>>(Vb, Vt, SS, DHH);
  k_attn<<<dim3((SS / QT) * BB * HH), 256, 0, stream>>>(Qb, Kb, Vt, Ocat);
  k_proj<<<dim3(DD / 128, BB * SS / 128), 256, 0, stream>>>(Ocat, wot, bo, out);
}

// Round 4
// 141.070 us; speedup vs baseline: 1.6267x; 1.0795x over previous
//
#include <hip/hip_runtime.h>
#include <hip/hip_bf16.h>

#define BB 2
#define SS 2048
#define DD 1024
#define HH 16
#define DHH 64

typedef __attribute__((ext_vector_type(8))) __bf16 bf16x8;
typedef __attribute__((ext_vector_type(4))) float f32x4;
typedef __attribute__((ext_vector_type(16))) float f32x16;
typedef __attribute__((ext_vector_type(4))) int i32x4;
typedef __attribute__((ext_vector_type(4))) unsigned int u32x4;

#define MFMA16 __builtin_amdgcn_mfma_f32_16x16x32_bf16
#define MFMA32 __builtin_amdgcn_mfma_f32_32x32x16_bf16

__device__ __forceinline__ unsigned short f2b(float f) {
  __hip_bfloat16 h = __float2bfloat16(f);
  unsigned short u;
  __builtin_memcpy(&u, &h, 2);
  return u;
}

__device__ __forceinline__ float exp2_fast(float x) {
  float r;
  asm("v_exp_f32 %0, %1" : "=v"(r) : "v"(x));
  return r;
}

__device__ __forceinline__ unsigned int cvtpk_bf16(float lo, float hi) {
  unsigned int r;
  asm("v_cvt_pk_bf16_f32 %0, %1, %2" : "=v"(r) : "v"(lo), "v"(hi));
  return r;
}

// async global -> LDS, 16B per lane. LDS dest = wave-uniform base + lane*16.
__device__ __forceinline__ void gl_lds16(const void* g, void* l) {
  __builtin_amdgcn_global_load_lds((const __attribute__((address_space(1))) void*)g,
                                   (__attribute__((address_space(3))) void*)l, 16, 0, 0);
}

// ---------------- cast fp32 -> bf16 (x4 vectorized) ----------------
__global__ __launch_bounds__(256) void k_cast(const float* __restrict__ in,
                                              unsigned short* __restrict__ out, int n4) {
  int i = blockIdx.x * blockDim.x + threadIdx.x;
  if (i >= n4) return;
  float4 v = ((const float4*)in)[i];
  ushort4 o;
  o.x = f2b(v.x); o.y = f2b(v.y); o.z = f2b(v.z); o.w = f2b(v.w);
  ((ushort4*)out)[i] = o;
}

// ------- transpose+cast fp32 [R][C] -> bf16 [C][R], generic (z batches) -------
__global__ __launch_bounds__(256) void k_tcast(const float* __restrict__ in,
                                               unsigned short* __restrict__ out, int R, int C) {
  __shared__ float t[32][33];
  size_t mb = (size_t)blockIdx.z * R * C;
  const float* im = in + mb;
  unsigned short* om = out + mb;
  int c0 = blockIdx.x * 32, r0 = blockIdx.y * 32;
  int tx = threadIdx.x & 31, ty = threadIdx.x >> 5;
#pragma unroll
  for (int rr = ty; rr < 32; rr += 8)
    t[rr][tx] = im[(size_t)(r0 + rr) * C + c0 + tx];
  __syncthreads();
#pragma unroll
  for (int rr = ty; rr < 32; rr += 8)
    om[(size_t)(c0 + rr) * R + r0 + tx] = f2b(t[tx][rr]);
}

// ------- merged transpose+cast of Wq,Wk,Wv: z = 0..47 selects (weight, head) -------
__global__ __launch_bounds__(256) void k_tcast3(const float* __restrict__ Wq,
                                                const float* __restrict__ Wk,
                                                const float* __restrict__ Wv,
                                                unsigned short* __restrict__ out) {
  __shared__ float t[32][33];
  int z = blockIdx.z;
  const float* im = (z < 16 ? Wq : (z < 32 ? Wk : Wv)) + (size_t)(z & 15) * DD * DHH;
  unsigned short* om = out + (size_t)z * DD * DHH;
  int c0 = blockIdx.x * 32, r0 = blockIdx.y * 32;
  int tx = threadIdx.x & 31, ty = threadIdx.x >> 5;
#pragma unroll
  for (int rr = ty; rr < 32; rr += 8)
    t[rr][tx] = im[(size_t)(r0 + rr) * DHH + c0 + tx];
  __syncthreads();
#pragma unroll
  for (int rr = ty; rr < 32; rr += 8)
    om[(size_t)(c0 + rr) * DD + r0 + tx] = f2b(t[tx][rr]);
}

// ---------------- QKV GEMM: 128x128 tile, BK=64, global_load_lds ----------------
// A: xb bf16 [4096][1024]. Wt: [3072][1024] (N-major, K contiguous).
// Q pre-scaled by 1/sqrt(DH)*log2(e). V blocks (sel==2) swap MFMA operands
// so D = [d][s] and write Vt [B*H][DH][S] directly (kills the transpose kernel).
__global__ __launch_bounds__(256) void k_qkv(const unsigned short* __restrict__ A,
                                             const unsigned short* __restrict__ Wt,
                                             const float* __restrict__ bq,
                                             const float* __restrict__ bk,
                                             const float* __restrict__ bv,
                                             unsigned short* __restrict__ Qb,
                                             unsigned short* __restrict__ Kb,
                                             unsigned short* __restrict__ Vtb) {
  __shared__ __align__(16) unsigned short As[128 * 64];
  __shared__ __align__(16) unsigned short Bs[128 * 64];
  int tid = threadIdx.x;
  int w = tid >> 6, l = tid & 63, lr = l & 15, lg = l >> 4;
  int wr = w >> 1, wc = w & 1;
  int col0 = blockIdx.x * 128, row0 = blockIdx.y * 128;
  int sel = col0 >> 10;
  bool vsel = (sel == 2);
  const float* biasp = sel == 0 ? bq : (sel == 1 ? bk : bv);
  unsigned short* outp = sel == 0 ? Qb : Kb;
  float qscale = sel == 0 ? 0.18033688011112042f : 1.0f;  // 0.125 * log2(e)

  int r8 = l >> 3, c8 = l & 7;
  const unsigned short* Ab = A + (size_t)(row0 + w * 32 + r8) * DD + c8 * 8;
  const unsigned short* Bb = Wt + (size_t)(col0 + w * 32 + r8) * DD + c8 * 8;

  f32x4 zero = {0.f, 0.f, 0.f, 0.f};
  f32x4 acc[4][4];
#pragma unroll
  for (int m = 0; m < 4; m++)
#pragma unroll
    for (int n = 0; n < 4; n++) acc[m][n] = zero;

  for (int k0 = 0; k0 < DD; k0 += 64) {
    __syncthreads();
#pragma unroll
    for (int c = 0; c < 4; c++) {
      gl_lds16(Ab + (size_t)c * 8 * DD + k0, (char*)As + (w * 32 + c * 8) * 128);
      gl_lds16(Bb + (size_t)c * 8 * DD + k0, (char*)Bs + (w * 32 + c * 8) * 128);
    }
    __syncthreads();
#pragma unroll
    for (int kk = 0; kk < 2; kk++) {
      bf16x8 af[4], bfr[4];
#pragma unroll
      for (int m = 0; m < 4; m++)
        af[m] = *(const bf16x8*)&As[(wr * 64 + m * 16 + lr) * 64 + kk * 32 + lg * 8];
#pragma unroll
      for (int n = 0; n < 4; n++)
        bfr[n] = *(const bf16x8*)&Bs[(wc * 64 + n * 16 + lr) * 64 + kk * 32 + lg * 8];
      if (!vsel) {
#pragma unroll
        for (int m = 0; m < 4; m++)
#pragma unroll
          for (int n = 0; n < 4; n++)
            acc[m][n] = MFMA16(af[m], bfr[n], acc[m][n], 0, 0, 0);
      } else {
#pragma unroll
        for (int m = 0; m < 4; m++)
#pragma unroll
          for (int n = 0; n < 4; n++)
            acc[m][n] = MFMA16(bfr[n], af[m], acc[m][n], 0, 0, 0);
      }
    }
  }

  if (!vsel) {
#pragma unroll
    for (int n = 0; n < 4; n++) {
      int c = col0 + wc * 64 + n * 16 + lr;
      int h = (c >> 6) & 15;
      int d = c & 63;
      float bias = biasp[h * DHH + d];
#pragma unroll
      for (int m = 0; m < 4; m++) {
#pragma unroll
        for (int j = 0; j < 4; j++) {
          int row = row0 + wr * 64 + m * 16 + lg * 4 + j;
          int b = row >> 11, s = row & 2047;
          outp[((size_t)(b * HH + h) * SS + s) * DHH + d] = f2b((acc[m][n][j] + bias) * qscale);
        }
      }
    }
  } else {
    int b = row0 >> 11, s0 = row0 & 2047;
#pragma unroll
    for (int n = 0; n < 4; n++) {
#pragma unroll
      for (int j = 0; j < 4; j++) {
        int dl = wc * 64 + n * 16 + lg * 4 + j;
        int hh = ((col0 & 1023) + dl) >> 6;
        int d = dl & 63;
        float bias = bv[hh * DHH + d];
#pragma unroll
        for (int m = 0; m < 4; m++) {
          int sl = wr * 64 + m * 16 + lr;
          Vtb[((size_t)(b * HH + hh) * DHH + d) * SS + s0 + sl] = f2b(acc[m][n][j] + bias);
        }
      }
    }
  }
}

// ---------------- output projection GEMM: 128x128 tile ----------------
__global__ __launch_bounds__(256) void k_proj(const unsigned short* __restrict__ A,
                                              const unsigned short* __restrict__ Wt,
                                              const float* __restrict__ bo,
                                              float* __restrict__ out) {
  __shared__ __align__(16) unsigned short As[128 * 64];
  __shared__ __align__(16) unsigned short Bs[128 * 64];
  int tid = threadIdx.x;
  int w = tid >> 6, l = tid & 63, lr = l & 15, lg = l >> 4;
  int wr = w >> 1, wc = w & 1;
  int col0 = blockIdx.x * 128, row0 = blockIdx.y * 128;

  int r8 = l >> 3, c8 = l & 7;
  const unsigned short* Ab = A + (size_t)(row0 + w * 32 + r8) * DD + c8 * 8;
  const unsigned short* Bb = Wt + (size_t)(col0 + w * 32 + r8) * DD + c8 * 8;

  f32x4 zero = {0.f, 0.f, 0.f, 0.f};
  f32x4 acc[4][4];
#pragma unroll
  for (int m = 0; m < 4; m++)
#pragma unroll
    for (int n = 0; n < 4; n++) acc[m][n] = zero;

  for (int k0 = 0; k0 < DD; k0 += 64) {
    __syncthreads();
#pragma unroll
    for (int c = 0; c < 4; c++) {
      gl_lds16(Ab + (size_t)c * 8 * DD + k0, (char*)As + (w * 32 + c * 8) * 128);
      gl_lds16(Bb + (size_t)c * 8 * DD + k0, (char*)Bs + (w * 32 + c * 8) * 128);
    }
    __syncthreads();
#pragma unroll
    for (int kk = 0; kk < 2; kk++) {
      bf16x8 af[4], bfr[4];
#pragma unroll
      for (int m = 0; m < 4; m++)
        af[m] = *(const bf16x8*)&As[(wr * 64 + m * 16 + lr) * 64 + kk * 32 + lg * 8];
#pragma unroll
      for (int n = 0; n < 4; n++)
        bfr[n] = *(const bf16x8*)&Bs[(wc * 64 + n * 16 + lr) * 64 + kk * 32 + lg * 8];
#pragma unroll
      for (int m = 0; m < 4; m++)
#pragma unroll
        for (int n = 0; n < 4; n++)
          acc[m][n] = MFMA16(af[m], bfr[n], acc[m][n], 0, 0, 0);
    }
  }

#pragma unroll
  for (int n = 0; n < 4; n++) {
    int c = col0 + wc * 64 + n * 16 + lr;
    float bias = bo[c];
#pragma unroll
    for (int m = 0; m < 4; m++) {
#pragma unroll
      for (int j = 0; j < 4; j++) {
        int row = row0 + wr * 64 + m * 16 + lg * 4 + j;
        out[(size_t)row * DD + c] = acc[m][n][j] + bias;
      }
    }
  }
}

// ---------------- flash attention: KVB=128, dbuf gl_lds, tree softmax ----------------
#define QT 128
#define KVB 128
#define NTILE (SS / KVB)

__global__ __launch_bounds__(256, 2) void k_attn(const unsigned short* __restrict__ Q,
                                                 const unsigned short* __restrict__ K,
                                                 const unsigned short* __restrict__ Vt,
                                                 unsigned short* __restrict__ Ocat) {
  // [0,16K): Qs 128x128B (3-bit swz), reused as Os[128][72] in epilogue.
  // [16K,48K): K dbuf 2 x (128 rows x 128B, 3-bit swz).
  // [48K,80K): V dbuf 2 x (64 rows x 256B, 4-bit swz).
  __shared__ __align__(16) char sm[81920];

  int tid = threadIdx.x;
  int w = tid >> 6, lane = tid & 63;
  int q32 = lane & 31, hi = lane >> 5;
  bool lo = (hi == 0);

  int n = blockIdx.x;
  int bh = ((n & 7) << 2) | ((n >> 3) & 3);  // bijective; groups 4 bh per XCD slot
  int q0 = (n >> 5) * QT;
  int bi = bh >> 4, h = bh & 15;
  const unsigned short* Qm = Q + (size_t)bh * SS * DHH;
  const unsigned short* Km = K + (size_t)bh * SS * DHH;
  const unsigned short* Vm = Vt + (size_t)bh * DHH * SS;

  int l8r = lane >> 3, l8c = lane & 7;
  int cgK = l8c ^ l8r;  // pre-swizzled global chunk for 128B rows
  int l16r = lane >> 4, l16c = lane & 15;

  // ---- prologue: Q + K/V tile0 via async DMA ----
#pragma unroll
  for (int c = 0; c < 4; c++) {
    int base = w * 32 + c * 8;
    gl_lds16(Qm + (size_t)(q0 + base + l8r) * DHH + cgK * 8, sm + base * 128);
    gl_lds16(Km + (size_t)(base + l8r) * DHH + cgK * 8, sm + 16384 + base * 128);
  }
#pragma unroll
  for (int c = 0; c < 4; c++) {
    int based = w * 16 + c * 4;
    int cgV = l16c ^ (c * 4 + l16r);
    gl_lds16(Vm + (size_t)(based + l16r) * SS + cgV * 8, sm + 49152 + based * 256);
  }
  __syncthreads();

  // ---- Q fragments (B-operand), hoisted ----
  bf16x8 qf[4];
  {
    int r = w * 32 + q32;
    const char* qb = sm + r * 128;
    int sw = (r & 7) << 4;
#pragma unroll
    for (int ks = 0; ks < 4; ks++)
      qf[ks] = *(const bf16x8*)(qb + ((ks * 32 + hi * 16) ^ sw));
  }

  f32x16 oacc0 = {}, oacc1 = {};
  float m_ = -1e30f, l_ = 0.f;
  const int sw3 = (q32 & 7) << 4;
  const int sw4 = (q32 & 15) << 4;

#define MKPA(PB, u) do { \
    unsigned int x0 = cvtpk_bf16(PB[8*(u)+0], PB[8*(u)+1]); \
    unsigned int x1 = cvtpk_bf16(PB[8*(u)+2], PB[8*(u)+3]); \
    unsigned int y0 = cvtpk_bf16(PB[8*(u)+4], PB[8*(u)+5]); \
    unsigned int y1 = cvtpk_bf16(PB[8*(u)+6], PB[8*(u)+7]); \
    unsigned int sx0 = (unsigned int)__shfl_xor((int)x0, 32); \
    unsigned int sx1 = (unsigned int)__shfl_xor((int)x1, 32); \
    unsigned int sy0 = (unsigned int)__shfl_xor((int)y0, 32); \
    unsigned int sy1 = (unsigned int)__shfl_xor((int)y1, 32); \
    pa[0] = lo ? x0 : sy0; pa[1] = lo ? x1 : sy1; \
    pa[2] = lo ? sx0 : y0; pa[3] = lo ? sx1 : y1; \
  } while (0)

#define PVSTEP(s) do { \
    bf16x8 pf = *(bf16x8*)&pa; \
    bf16x8 vf0 = *(const bf16x8*)(Vc + (q32) * 256 + (((s) * 32 + hi * 16) ^ sw4)); \
    bf16x8 vf1 = *(const bf16x8*)(Vc + (32 + q32) * 256 + (((s) * 32 + hi * 16) ^ sw4)); \
    oacc0 = MFMA32(vf0, pf, oacc0, 0, 0, 0); \
    oacc1 = MFMA32(vf1, pf, oacc1, 0, 0, 0); \
  } while (0)

  for (int t = 0; t < NTILE; t++) {
    const char* Kc = sm + 16384 + (t & 1) * 16384;
    const char* Vc = sm + 49152 + (t & 1) * 16384;

    // issue next tile's DMA into the other buffer; flies under this tile's compute
    if (t + 1 < NTILE) {
      int kv0 = (t + 1) * KVB;
      char* kd = sm + 16384 + ((t + 1) & 1) * 16384;
      char* vd = sm + 49152 + ((t + 1) & 1) * 16384;
#pragma unroll
      for (int c = 0; c < 4; c++) {
        int base = w * 32 + c * 8;
        gl_lds16(Km + (size_t)(kv0 + base + l8r) * DHH + cgK * 8, kd + base * 128);
      }
#pragma unroll
      for (int c = 0; c < 4; c++) {
        int based = w * 16 + c * 4;
        int cgV = l16c ^ (c * 4 + l16r);
        gl_lds16(Vm + (size_t)(based + l16r) * SS + kv0 + cgV * 8, vd + based * 256);
      }
    }

    // ---- QK^T: mfma(K, Q) -> D[kv][q], q = lane&31. 16 MFMAs, 4 indep chains ----
    f32x16 p0 = {}, p1 = {}, p2 = {}, p3 = {};
    __builtin_amdgcn_s_setprio(1);
#pragma unroll
    for (int ks = 0; ks < 4; ks++) {
      int co = (ks * 32 + hi * 16) ^ sw3;
      bf16x8 k0 = *(const bf16x8*)(Kc + (q32) * 128 + co);
      bf16x8 k1 = *(const bf16x8*)(Kc + (32 + q32) * 128 + co);
      bf16x8 k2 = *(const bf16x8*)(Kc + (64 + q32) * 128 + co);
      bf16x8 k3 = *(const bf16x8*)(Kc + (96 + q32) * 128 + co);
      p0 = MFMA32(k0, qf[ks], p0, 0, 0, 0);
      p1 = MFMA32(k1, qf[ks], p1, 0, 0, 0);
      p2 = MFMA32(k2, qf[ks], p2, 0, 0, 0);
      p3 = MFMA32(k3, qf[ks], p3, 0, 0, 0);
    }
    __builtin_amdgcn_s_setprio(0);

    // ---- online softmax over 64 lane-local values (tree-shaped) ----
    float t16[16];
#pragma unroll
    for (int r = 0; r < 16; r++)
      t16[r] = fmaxf(fmaxf(p0[r], p1[r]), fmaxf(p2[r], p3[r]));
#pragma unroll
    for (int r = 0; r < 8; r++) t16[r] = fmaxf(t16[r], t16[r + 8]);
#pragma unroll
    for (int r = 0; r < 4; r++) t16[r] = fmaxf(t16[r], t16[r + 4]);
    float tmax = fmaxf(fmaxf(t16[0], t16[1]), fmaxf(t16[2], t16[3]));
    tmax = fmaxf(tmax, __shfl_xor(tmax, 32));

    if (__any(tmax > m_ + 8.0f)) {  // defer-max
      float nm = fmaxf(m_, tmax);
      float al = exp2_fast(m_ - nm);
      m_ = nm; l_ *= al;
#pragma unroll
      for (int r = 0; r < 16; r++) { oacc0[r] *= al; oacc1[r] *= al; }
    }

#pragma unroll
    for (int r = 0; r < 16; r++) p0[r] = exp2_fast(p0[r] - m_);
#pragma unroll
    for (int r = 0; r < 16; r++) p1[r] = exp2_fast(p1[r] - m_);
#pragma unroll
    for (int r = 0; r < 16; r++) p2[r] = exp2_fast(p2[r] - m_);
#pragma unroll
    for (int r = 0; r < 16; r++) p3[r] = exp2_fast(p3[r] - m_);
    float s16[16];
#pragma unroll
    for (int r = 0; r < 16; r++) s16[r] = (p0[r] + p1[r]) + (p2[r] + p3[r]);
#pragma unroll
    for (int r = 0; r < 8; r++) s16[r] += s16[r + 8];
#pragma unroll
    for (int r = 0; r < 4; r++) s16[r] += s16[r + 4];
    float ssum = (s16[0] + s16[1]) + (s16[2] + s16[3]);
    ssum += __shfl_xor(ssum, 32);
    l_ += ssum;

    // ---- PV: per 16-kv window, build pa (VALU) then 2 MFMAs — interleaved ----
    __builtin_amdgcn_s_setprio(1);
    u32x4 pa;
    MKPA(p0, 0); PVSTEP(0);
    MKPA(p0, 1); PVSTEP(1);
    MKPA(p1, 0); PVSTEP(2);
    MKPA(p1, 1); PVSTEP(3);
    MKPA(p2, 0); PVSTEP(4);
    MKPA(p2, 1); PVSTEP(5);
    MKPA(p3, 0); PVSTEP(6);
    MKPA(p3, 1); PVSTEP(7);
    __builtin_amdgcn_s_setprio(0);

    __syncthreads();  // drains next-tile DMA; separates buffer reuse
  }

  // ---- epilogue: normalize, transpose via LDS (reuse Q region), coalesced store ----
  float inv = 1.0f / l_;
  unsigned short* Os = (unsigned short*)sm;  // [128][72]
  int rowq = w * 32 + q32;
#pragma unroll
  for (int r = 0; r < 16; r++) {
    int d = (r & 3) + 8 * (r >> 2) + 4 * hi;
    Os[rowq * 72 + d] = f2b(oacc0[r] * inv);
    Os[rowq * 72 + 32 + d] = f2b(oacc1[r] * inv);
  }
  __syncthreads();
#pragma unroll
  for (int i = 0; i < 4; i++) {
    int ci = tid + i * 256;
    int r = ci >> 3, c = ci & 7;
    i32x4 v = *(const i32x4*)(Os + r * 72 + c * 8);
    *(i32x4*)(Ocat + ((size_t)(bi * SS + q0 + r)) * DD + h * DHH + c * 8) = v;
  }
}

extern "C" void kernel_launch(void* const* d_in, const int* in_sizes, int n_in,
                              void* d_out, int out_size, void* d_ws, size_t ws_size,
                              hipStream_t stream) {
  const float* x  = (const float*)d_in[0];
  const float* Wq = (const float*)d_in[1];
  const float* bq = (const float*)d_in[2];
  const float* Wk = (const float*)d_in[3];
  const float* bk = (const float*)d_in[4];
  const float* Wv = (const float*)d_in[5];
  const float* bv = (const float*)d_in[6];
  const float* Wo = (const float*)d_in[7];
  const float* bo = (const float*)d_in[8];
  float* out = (float*)d_out;

  char* ws = (char*)d_ws;
  unsigned short* xb    = (unsigned short*)(ws);                       // 8 MB
  unsigned short* wqkvt = (unsigned short*)(ws + (size_t)(8u  << 20)); // 6 MB
  unsigned short* wot   = (unsigned short*)(ws + (size_t)(14u << 20)); // 2 MB
  unsigned short* Qb    = (unsigned short*)(ws + (size_t)(16u << 20)); // 8 MB
  unsigned short* Kb    = (unsigned short*)(ws + (size_t)(24u << 20)); // 8 MB
  unsigned short* Vt    = (unsigned short*)(ws + (size_t)(32u << 20)); // 8 MB
  unsigned short* Ocat  = (unsigned short*)(ws + (size_t)(40u << 20)); // 8 MB

  k_cast<<<(BB * SS * DD / 4 + 255) / 256, 256, 0, stream>>>(x, xb, BB * SS * DD / 4);
  k_tcast3<<<dim3(DHH / 32, DD / 32, 48), 256, 0, stream>>>(Wq, Wk, Wv, wqkvt);
  k_tcast<<<dim3(DD / 32, DD / 32, 1), 256, 0, stream>>>(Wo, wot, DD, DD);
  k_qkv<<<dim3(3 * DD / 128, BB * SS / 128), 256, 0, stream>>>(xb, wqkvt, bq, bk, bv, Qb, Kb, Vt);
  k_attn<<<dim3((SS / QT) * BB * HH), 256, 0, stream>>>(Qb, Kb, Vt, Ocat);
  k_proj<<<dim3(DD / 128, BB * SS / 128), 256, 0, stream>>>(Ocat, wot, bo, out);
}